// Round 5
// baseline (681.196 us; speedup 1.0000x reference)
//
#include <hip/hip_runtime.h>

// z <- tanh(z @ W^T + x), 50 fixed-point steps. B=16384, D=512.
// Persistent-block: each of 256 blocks owns 64 rows of z in a SINGLE 64 KB
// bf16 LDS buffer with two barriers per iteration (round-0 structure: the
// double-buffer/single-barrier variant regressed 610->675 us and blew HBM
// FETCH 19 MB->495 MB; phase-locked waves keep x + W resident and the LDS
// port phase-separated).
// Kept from rounds 2-4 (verified correct, pure VALU savings):
//  - W pre-scaled by K = 2*log2(e), bf16 MFMA A-fragments in d_ws (512 KB,
//    L2-resident), streamed every iteration (register-resident W is
//    impossible: allocator caps at 128 arch VGPRs, rounds 1-3 spilled GBs).
//  - epilogue s = fmaf(x, K, acc); tanh = 1 - 2/(exp2(med3(s,+-CL))+1)
//    [3 VALU + 2 trans per element]; pack via v_cvt_pk_bf16_f32 (1 op/pair).

typedef short s8v  __attribute__((ext_vector_type(8)));   // 8 bf16 = 4 VGPRs
typedef float f32x16 __attribute__((ext_vector_type(16)));

#define BATCH 16384
#define DIM   512
#define TM    64        // rows per block
#define NITER 50        // 1 init step + 49 GEMM steps

#define KSC 2.8853900817779268f    // 2*log2(e)
#define KCL 28.853900817779268f    // 10*KSC: tanh(+-10) == +-1 in fp32

__device__ __forceinline__ unsigned short f2bf(float f) {
    unsigned int u = __float_as_uint(f);
    u += 0x7fffu + ((u >> 16) & 1u);          // round-to-nearest-even
    return (unsigned short)(u >> 16);
}

// W (fp32 [512][512] row-major) -> K-prescaled bf16 A-fragments for
// v_mfma_f32_32x32x16_bf16. Granule tid = (jt*32 + ks)*64 + lane holds
// K*W[j = 32*jt + (lane&31)][k = 16*ks + 8*(lane>>5) .. +8] as 16 B.
__global__ void wprep_kernel(const float* __restrict__ W, unsigned short* __restrict__ Wf) {
    int tid = blockIdx.x * blockDim.x + threadIdx.x;   // 0..32767
    int jt  = tid >> 11;
    int rem = tid & 2047;
    int ks  = rem >> 6;
    int L   = rem & 63;
    int j   = jt * 32 + (L & 31);
    int k   = ks * 16 + (L >> 5) * 8;
    const float* src = W + j * DIM + k;
    uint4 p;
    p.x = (unsigned)f2bf(src[0] * KSC) | ((unsigned)f2bf(src[1] * KSC) << 16);
    p.y = (unsigned)f2bf(src[2] * KSC) | ((unsigned)f2bf(src[3] * KSC) << 16);
    p.z = (unsigned)f2bf(src[4] * KSC) | ((unsigned)f2bf(src[5] * KSC) << 16);
    p.w = (unsigned)f2bf(src[6] * KSC) | ((unsigned)f2bf(src[7] * KSC) << 16);
    ((uint4*)Wf)[tid] = p;
}

// LDS z layout: row r x 512 bf16, 64 chunks of 16 B per row, XOR swizzle
// chunk' = chunk ^ (r & 7) -> spreads bank groups for ds_read_b128 / writes.
__device__ __forceinline__ int z_addr(int r, int j) {   // element index
    int c  = j >> 3;
    int lo = j & 7;
    return r * DIM + (((c ^ (r & 7)) << 3) | lo);
}

__device__ __forceinline__ unsigned pk_bf16(float lo, float hi) {
    unsigned r;
    asm("v_cvt_pk_bf16_f32 %0, %1, %2" : "=v"(r) : "v"(lo), "v"(hi));  // RNE
    return r;
}

// s is the ALREADY K-SCALED argument: tanh(v) where s = K*v.
__device__ __forceinline__ float tanh_pre(float s) {
    s = __builtin_amdgcn_fmed3f(s, -KCL, KCL);
    float t = __builtin_amdgcn_exp2f(s);
    float q = __builtin_amdgcn_rcpf(t + 1.0f);
    return fmaf(-2.0f, q, 1.0f);            // (t-1)/(t+1) == 1 - 2/(t+1)
}

__device__ __forceinline__ f32x16 zero16() {
    f32x16 v;
#pragma unroll
    for (int i = 0; i < 16; ++i) v[i] = 0.0f;
    return v;
}

__global__ __launch_bounds__(512, 2)
void fixpoint_kernel(const float* __restrict__ x,
                     const unsigned short* __restrict__ Wf,
                     float* __restrict__ out) {
    __shared__ alignas(16) unsigned short zt[TM * DIM];   // 64 KB single buffer

    const int tid  = threadIdx.x;
    const int lane = tid & 63;
    const int w    = tid >> 6;       // wave 0..7, owns j-slab [64w, 64w+64)
    const int l31  = lane & 31;
    const int h    = lane >> 5;      // k-half for A/B fragments
    const int r0   = blockIdx.x * TM;
    const int jt0  = 2 * w;
    const int jb0  = 64 * w;
    const int swz  = l31 & 7;

    const s8v* Wfv = (const s8v*)Wf;

    // ---- step 1: z = tanh(x) = tanh_pre(K*x), coalesced float4 reads ----
    for (int base = tid * 4; base < TM * DIM; base += 512 * 4) {
        int r = base >> 9, j = base & (DIM - 1);
        float4 xv = *(const float4*)&x[(size_t)(r0 + r) * DIM + j];
        uint2 p;
        p.x = pk_bf16(tanh_pre(xv.x * KSC), tanh_pre(xv.y * KSC));
        p.y = pk_bf16(tanh_pre(xv.z * KSC), tanh_pre(xv.w * KSC));
        *(uint2*)&zt[z_addr(r, j)] = p;   // j%4==0 -> 8B aligned
    }
    __syncthreads();

    const float* xr0 = x + (size_t)(r0 + l31) * DIM;
    const float* xr1 = x + (size_t)(r0 + l31 + 32) * DIM;

    f32x16 ac0, ac1, ac2, ac3;

    // acc fragment layout: col = lane&31 -> z-row; row = (reg&3)+8*(reg>>2)+4*h -> j
    auto gemm = [&]() {
        ac0 = zero16(); ac1 = zero16(); ac2 = zero16(); ac3 = zero16();
#pragma unroll 4
        for (int ks = 0; ks < 32; ++ks) {
            s8v a0 = Wfv[(jt0 * 32 + ks) * 64 + lane];
            s8v a1 = Wfv[((jt0 + 1) * 32 + ks) * 64 + lane];
            const int c = ((2 * ks + h) ^ swz) << 3;
            s8v b0 = *(const s8v*)&zt[l31 * DIM + c];
            s8v b1 = *(const s8v*)&zt[(l31 + 32) * DIM + c];
            ac0 = __builtin_amdgcn_mfma_f32_32x32x16_bf16(a0, b0, ac0, 0, 0, 0);
            ac1 = __builtin_amdgcn_mfma_f32_32x32x16_bf16(a0, b1, ac1, 0, 0, 0);
            ac2 = __builtin_amdgcn_mfma_f32_32x32x16_bf16(a1, b0, ac2, 0, 0, 0);
            ac3 = __builtin_amdgcn_mfma_f32_32x32x16_bf16(a1, b1, ac3, 0, 0, 0);
        }
    };

    auto epi_z = [&]() {
#pragma unroll
        for (int g = 0; g < 4; ++g) {
            const int j0 = jb0 + 8 * g + 4 * h;
            float4 x0 = *(const float4*)&xr0[j0];
            float4 x1 = *(const float4*)&xr1[j0];
            float4 x2 = *(const float4*)&xr0[j0 + 32];
            float4 x3 = *(const float4*)&xr1[j0 + 32];
            uint2 p;
            p.x = pk_bf16(tanh_pre(fmaf(x0.x, KSC, ac0[4*g+0])),
                          tanh_pre(fmaf(x0.y, KSC, ac0[4*g+1])));
            p.y = pk_bf16(tanh_pre(fmaf(x0.z, KSC, ac0[4*g+2])),
                          tanh_pre(fmaf(x0.w, KSC, ac0[4*g+3])));
            *(uint2*)&zt[z_addr(l31, j0)] = p;
            p.x = pk_bf16(tanh_pre(fmaf(x1.x, KSC, ac1[4*g+0])),
                          tanh_pre(fmaf(x1.y, KSC, ac1[4*g+1])));
            p.y = pk_bf16(tanh_pre(fmaf(x1.z, KSC, ac1[4*g+2])),
                          tanh_pre(fmaf(x1.w, KSC, ac1[4*g+3])));
            *(uint2*)&zt[z_addr(l31 + 32, j0)] = p;
            p.x = pk_bf16(tanh_pre(fmaf(x2.x, KSC, ac2[4*g+0])),
                          tanh_pre(fmaf(x2.y, KSC, ac2[4*g+1])));
            p.y = pk_bf16(tanh_pre(fmaf(x2.z, KSC, ac2[4*g+2])),
                          tanh_pre(fmaf(x2.w, KSC, ac2[4*g+3])));
            *(uint2*)&zt[z_addr(l31, j0 + 32)] = p;
            p.x = pk_bf16(tanh_pre(fmaf(x3.x, KSC, ac3[4*g+0])),
                          tanh_pre(fmaf(x3.y, KSC, ac3[4*g+1])));
            p.y = pk_bf16(tanh_pre(fmaf(x3.z, KSC, ac3[4*g+2])),
                          tanh_pre(fmaf(x3.w, KSC, ac3[4*g+3])));
            *(uint2*)&zt[z_addr(l31 + 32, j0 + 32)] = p;
        }
    };

    auto epi_out = [&]() {
        float* o0 = out + (size_t)(r0 + l31) * DIM;
        float* o1 = out + (size_t)(r0 + l31 + 32) * DIM;
#pragma unroll
        for (int g = 0; g < 4; ++g) {
            const int j0 = jb0 + 8 * g + 4 * h;
            float4 x0 = *(const float4*)&xr0[j0];
            float4 x1 = *(const float4*)&xr1[j0];
            float4 x2 = *(const float4*)&xr0[j0 + 32];
            float4 x3 = *(const float4*)&xr1[j0 + 32];
            float4 v;
            v.x = tanh_pre(fmaf(x0.x, KSC, ac0[4*g+0]));
            v.y = tanh_pre(fmaf(x0.y, KSC, ac0[4*g+1]));
            v.z = tanh_pre(fmaf(x0.z, KSC, ac0[4*g+2]));
            v.w = tanh_pre(fmaf(x0.w, KSC, ac0[4*g+3]));
            *(float4*)&o0[j0] = v;
            v.x = tanh_pre(fmaf(x1.x, KSC, ac1[4*g+0]));
            v.y = tanh_pre(fmaf(x1.y, KSC, ac1[4*g+1]));
            v.z = tanh_pre(fmaf(x1.z, KSC, ac1[4*g+2]));
            v.w = tanh_pre(fmaf(x1.w, KSC, ac1[4*g+3]));
            *(float4*)&o1[j0] = v;
            v.x = tanh_pre(fmaf(x2.x, KSC, ac2[4*g+0]));
            v.y = tanh_pre(fmaf(x2.y, KSC, ac2[4*g+1]));
            v.z = tanh_pre(fmaf(x2.z, KSC, ac2[4*g+2]));
            v.w = tanh_pre(fmaf(x2.w, KSC, ac2[4*g+3]));
            *(float4*)&o0[j0 + 32] = v;
            v.x = tanh_pre(fmaf(x3.x, KSC, ac3[4*g+0]));
            v.y = tanh_pre(fmaf(x3.y, KSC, ac3[4*g+1]));
            v.z = tanh_pre(fmaf(x3.z, KSC, ac3[4*g+2]));
            v.w = tanh_pre(fmaf(x3.w, KSC, ac3[4*g+3]));
            *(float4*)&o1[j0 + 32] = v;
        }
    };

#pragma unroll 1
    for (int it = 0; it < NITER - 2; ++it) {     // 48 LDS->LDS steps
        gemm();
        __syncthreads();   // all waves done reading zt
        epi_z();
        __syncthreads();   // z_next visible before next iteration reads
    }
    // ---- step 50: fp32 store to out ----
    gemm();
    epi_out();
}

extern "C" void kernel_launch(void* const* d_in, const int* in_sizes, int n_in,
                              void* d_out, int out_size, void* d_ws, size_t ws_size,
                              hipStream_t stream) {
    const float* x = (const float*)d_in[0];   // [16384, 512] fp32
    const float* W = (const float*)d_in[1];   // [512, 512] fp32
    float* out = (float*)d_out;               // [16384, 512] fp32
    unsigned short* Wf = (unsigned short*)d_ws;   // 512 KB bf16 fragments (K-prescaled)

    wprep_kernel<<<128, 256, 0, stream>>>(W, Wf);
    fixpoint_kernel<<<BATCH / TM, 512, 0, stream>>>(x, Wf, out);
}

// Round 6
// 520.643 us; speedup vs baseline: 1.3084x; 1.3084x over previous
//
#include <hip/hip_runtime.h>

// z <- tanh(z @ W^T + x), 50 fixed-point steps. B=16384, D=512.
// Persistent-block: each of 256 blocks owns 64 rows of z in a SINGLE 64 KB
// bf16 LDS buffer, two barriers per iteration (phase-locked waves).
// NEW (round 6): x is staged ONCE into LDS as fp16 (64 KB, XOR-swizzled
// 8-B granules) -> the epilogue does ZERO global loads. Rounds 4/5 showed
// 496 MB/launch of HBM re-fetch (~10 MB/iter) from per-iter global x reads:
// per-XCD working set (x 4 MB + W 0.5 MB) sits at L2 capacity and thrashes.
// fp16 x error (~2.4e-4 rel) is small vs the bf16-z noise floor.
// Kept (verified): W pre-scaled by K = 2*log2(e) as bf16 MFMA A-fragments in
// d_ws (512 KB, L2-resident, streamed -- register-resident W impossible:
// allocator caps at 128 arch VGPRs, rounds 1-3 spilled GBs);
// epilogue s = fmaf((float)x_f16, K, acc) [v_fma_mix eligible];
// tanh = 1 - 2/(exp2(med3(s,+-CL))+1); pack via v_cvt_pk_bf16_f32.

typedef short s8v  __attribute__((ext_vector_type(8)));   // 8 bf16 = 4 VGPRs
typedef float f32x16 __attribute__((ext_vector_type(16)));
typedef _Float16 h4 __attribute__((ext_vector_type(4)));  // 4 fp16 = 8 B

#define BATCH 16384
#define DIM   512
#define TM    64        // rows per block
#define NITER 50        // 1 init step + 49 GEMM steps

#define KSC 2.8853900817779268f    // 2*log2(e)
#define KCL 28.853900817779268f    // 10*KSC: tanh(+-10) == +-1 in fp32

__device__ __forceinline__ unsigned short f2bf(float f) {
    unsigned int u = __float_as_uint(f);
    u += 0x7fffu + ((u >> 16) & 1u);          // round-to-nearest-even
    return (unsigned short)(u >> 16);
}

// W (fp32 [512][512] row-major) -> K-prescaled bf16 A-fragments for
// v_mfma_f32_32x32x16_bf16. Granule tid = (jt*32 + ks)*64 + lane holds
// K*W[j = 32*jt + (lane&31)][k = 16*ks + 8*(lane>>5) .. +8] as 16 B.
__global__ void wprep_kernel(const float* __restrict__ W, unsigned short* __restrict__ Wf) {
    int tid = blockIdx.x * blockDim.x + threadIdx.x;   // 0..32767
    int jt  = tid >> 11;
    int rem = tid & 2047;
    int ks  = rem >> 6;
    int L   = rem & 63;
    int j   = jt * 32 + (L & 31);
    int k   = ks * 16 + (L >> 5) * 8;
    const float* src = W + j * DIM + k;
    uint4 p;
    p.x = (unsigned)f2bf(src[0] * KSC) | ((unsigned)f2bf(src[1] * KSC) << 16);
    p.y = (unsigned)f2bf(src[2] * KSC) | ((unsigned)f2bf(src[3] * KSC) << 16);
    p.z = (unsigned)f2bf(src[4] * KSC) | ((unsigned)f2bf(src[5] * KSC) << 16);
    p.w = (unsigned)f2bf(src[6] * KSC) | ((unsigned)f2bf(src[7] * KSC) << 16);
    ((uint4*)Wf)[tid] = p;
}

// LDS z layout: row r x 512 bf16, 64 chunks of 16 B per row, XOR swizzle
// chunk' = chunk ^ (r & 7) -> spreads bank groups for ds_read_b128 / writes.
__device__ __forceinline__ int z_addr(int r, int j) {   // element index
    int c  = j >> 3;
    int lo = j & 7;
    return r * DIM + (((c ^ (r & 7)) << 3) | lo);
}

// LDS x layout: row r x 128 granules of 4 fp16 (8 B), granule' = g ^ (r&15)
// -> 32 consecutive-row lanes reading one granule column spread over 16
// distinct bank pairs (~free 2-way per half-wave, <=4-way per wave).
__device__ __forceinline__ int x_addr(int r, int g) {   // granule index
    return r * 128 + (g ^ (r & 15));
}

__device__ __forceinline__ unsigned pk_bf16(float lo, float hi) {
    unsigned r;
    asm("v_cvt_pk_bf16_f32 %0, %1, %2" : "=v"(r) : "v"(lo), "v"(hi));  // RNE
    return r;
}

// s is the ALREADY K-SCALED argument: tanh(v) where s = K*v.
__device__ __forceinline__ float tanh_pre(float s) {
    s = __builtin_amdgcn_fmed3f(s, -KCL, KCL);
    float t = __builtin_amdgcn_exp2f(s);
    float q = __builtin_amdgcn_rcpf(t + 1.0f);
    return fmaf(-2.0f, q, 1.0f);            // (t-1)/(t+1) == 1 - 2/(t+1)
}

__device__ __forceinline__ f32x16 zero16() {
    f32x16 v;
#pragma unroll
    for (int i = 0; i < 16; ++i) v[i] = 0.0f;
    return v;
}

__global__ __launch_bounds__(512, 2)
void fixpoint_kernel(const float* __restrict__ x,
                     const unsigned short* __restrict__ Wf,
                     float* __restrict__ out) {
    __shared__ alignas(16) unsigned short zt[TM * DIM];   // 64 KB z (bf16)
    __shared__ alignas(16) h4 xsh[TM * (DIM / 4)];        // 64 KB x (fp16)

    const int tid  = threadIdx.x;
    const int lane = tid & 63;
    const int w    = tid >> 6;       // wave 0..7, owns j-slab [64w, 64w+64)
    const int l31  = lane & 31;
    const int h    = lane >> 5;      // k-half for A/B fragments
    const int r0   = blockIdx.x * TM;
    const int jt0  = 2 * w;
    const int jb0  = 64 * w;
    const int swz  = l31 & 7;        // z-row swizzle key
    const int sx   = l31 & 15;       // x-row swizzle key (same for r and r+32)

    const s8v* Wfv = (const s8v*)Wf;

    // ---- step 1: z = tanh(K*x) AND stage x -> fp16 LDS (only global x read) ----
    for (int base = tid * 4; base < TM * DIM; base += 512 * 4) {
        int r = base >> 9, j = base & (DIM - 1);
        float4 xv = *(const float4*)&x[(size_t)(r0 + r) * DIM + j];
        uint2 p;
        p.x = pk_bf16(tanh_pre(xv.x * KSC), tanh_pre(xv.y * KSC));
        p.y = pk_bf16(tanh_pre(xv.z * KSC), tanh_pre(xv.w * KSC));
        *(uint2*)&zt[z_addr(r, j)] = p;   // j%4==0 -> 8B aligned
        h4 hx;
        hx[0] = (_Float16)xv.x; hx[1] = (_Float16)xv.y;
        hx[2] = (_Float16)xv.z; hx[3] = (_Float16)xv.w;
        xsh[x_addr(r, j >> 2)] = hx;
    }
    __syncthreads();

    f32x16 ac0, ac1, ac2, ac3;

    // acc fragment layout: col = lane&31 -> z-row; row = (reg&3)+8*(reg>>2)+4*h -> j
    auto gemm = [&]() {
        ac0 = zero16(); ac1 = zero16(); ac2 = zero16(); ac3 = zero16();
#pragma unroll 4
        for (int ks = 0; ks < 32; ++ks) {
            s8v a0 = Wfv[(jt0 * 32 + ks) * 64 + lane];
            s8v a1 = Wfv[((jt0 + 1) * 32 + ks) * 64 + lane];
            const int c = ((2 * ks + h) ^ swz) << 3;
            s8v b0 = *(const s8v*)&zt[l31 * DIM + c];
            s8v b1 = *(const s8v*)&zt[(l31 + 32) * DIM + c];
            ac0 = __builtin_amdgcn_mfma_f32_32x32x16_bf16(a0, b0, ac0, 0, 0, 0);
            ac1 = __builtin_amdgcn_mfma_f32_32x32x16_bf16(a0, b1, ac1, 0, 0, 0);
            ac2 = __builtin_amdgcn_mfma_f32_32x32x16_bf16(a1, b0, ac2, 0, 0, 0);
            ac3 = __builtin_amdgcn_mfma_f32_32x32x16_bf16(a1, b1, ac3, 0, 0, 0);
        }
    };

    // Per g: j0 = jb0 + 8g + 4h; x granule G0 = j0/4, +8 for the j0+32 block.
    auto epi_z = [&]() {
#pragma unroll
        for (int g = 0; g < 4; ++g) {
            const int j0 = jb0 + 8 * g + 4 * h;
            const int G0 = j0 >> 2;
            h4 x0 = xsh[x_addr(l31,      G0)];
            h4 x1 = xsh[x_addr(l31 + 32, G0)];
            h4 x2 = xsh[x_addr(l31,      G0 + 8)];
            h4 x3 = xsh[x_addr(l31 + 32, G0 + 8)];
            uint2 p;
            p.x = pk_bf16(tanh_pre(fmaf((float)x0[0], KSC, ac0[4*g+0])),
                          tanh_pre(fmaf((float)x0[1], KSC, ac0[4*g+1])));
            p.y = pk_bf16(tanh_pre(fmaf((float)x0[2], KSC, ac0[4*g+2])),
                          tanh_pre(fmaf((float)x0[3], KSC, ac0[4*g+3])));
            *(uint2*)&zt[z_addr(l31, j0)] = p;
            p.x = pk_bf16(tanh_pre(fmaf((float)x1[0], KSC, ac1[4*g+0])),
                          tanh_pre(fmaf((float)x1[1], KSC, ac1[4*g+1])));
            p.y = pk_bf16(tanh_pre(fmaf((float)x1[2], KSC, ac1[4*g+2])),
                          tanh_pre(fmaf((float)x1[3], KSC, ac1[4*g+3])));
            *(uint2*)&zt[z_addr(l31 + 32, j0)] = p;
            p.x = pk_bf16(tanh_pre(fmaf((float)x2[0], KSC, ac2[4*g+0])),
                          tanh_pre(fmaf((float)x2[1], KSC, ac2[4*g+1])));
            p.y = pk_bf16(tanh_pre(fmaf((float)x2[2], KSC, ac2[4*g+2])),
                          tanh_pre(fmaf((float)x2[3], KSC, ac2[4*g+3])));
            *(uint2*)&zt[z_addr(l31, j0 + 32)] = p;
            p.x = pk_bf16(tanh_pre(fmaf((float)x3[0], KSC, ac3[4*g+0])),
                          tanh_pre(fmaf((float)x3[1], KSC, ac3[4*g+1])));
            p.y = pk_bf16(tanh_pre(fmaf((float)x3[2], KSC, ac3[4*g+2])),
                          tanh_pre(fmaf((float)x3[3], KSC, ac3[4*g+3])));
            *(uint2*)&zt[z_addr(l31 + 32, j0 + 32)] = p;
        }
    };

    auto epi_out = [&]() {
        float* o0 = out + (size_t)(r0 + l31) * DIM;
        float* o1 = out + (size_t)(r0 + l31 + 32) * DIM;
#pragma unroll
        for (int g = 0; g < 4; ++g) {
            const int j0 = jb0 + 8 * g + 4 * h;
            const int G0 = j0 >> 2;
            h4 x0 = xsh[x_addr(l31,      G0)];
            h4 x1 = xsh[x_addr(l31 + 32, G0)];
            h4 x2 = xsh[x_addr(l31,      G0 + 8)];
            h4 x3 = xsh[x_addr(l31 + 32, G0 + 8)];
            float4 v;
            v.x = tanh_pre(fmaf((float)x0[0], KSC, ac0[4*g+0]));
            v.y = tanh_pre(fmaf((float)x0[1], KSC, ac0[4*g+1]));
            v.z = tanh_pre(fmaf((float)x0[2], KSC, ac0[4*g+2]));
            v.w = tanh_pre(fmaf((float)x0[3], KSC, ac0[4*g+3]));
            *(float4*)&o0[j0] = v;
            v.x = tanh_pre(fmaf((float)x1[0], KSC, ac1[4*g+0]));
            v.y = tanh_pre(fmaf((float)x1[1], KSC, ac1[4*g+1]));
            v.z = tanh_pre(fmaf((float)x1[2], KSC, ac1[4*g+2]));
            v.w = tanh_pre(fmaf((float)x1[3], KSC, ac1[4*g+3]));
            *(float4*)&o1[j0] = v;
            v.x = tanh_pre(fmaf((float)x2[0], KSC, ac2[4*g+0]));
            v.y = tanh_pre(fmaf((float)x2[1], KSC, ac2[4*g+1]));
            v.z = tanh_pre(fmaf((float)x2[2], KSC, ac2[4*g+2]));
            v.w = tanh_pre(fmaf((float)x2[3], KSC, ac2[4*g+3]));
            *(float4*)&o0[j0 + 32] = v;
            v.x = tanh_pre(fmaf((float)x3[0], KSC, ac3[4*g+0]));
            v.y = tanh_pre(fmaf((float)x3[1], KSC, ac3[4*g+1]));
            v.z = tanh_pre(fmaf((float)x3[2], KSC, ac3[4*g+2]));
            v.w = tanh_pre(fmaf((float)x3[3], KSC, ac3[4*g+3]));
            *(float4*)&o1[j0 + 32] = v;
        }
    };

#pragma unroll 1
    for (int it = 0; it < NITER - 2; ++it) {     // 48 LDS->LDS steps
        gemm();
        __syncthreads();   // all waves done reading zt
        epi_z();
        __syncthreads();   // z_next visible before next iteration reads
    }
    // ---- step 50: fp32 store to out ----
    gemm();
    epi_out();
}

extern "C" void kernel_launch(void* const* d_in, const int* in_sizes, int n_in,
                              void* d_out, int out_size, void* d_ws, size_t ws_size,
                              hipStream_t stream) {
    const float* x = (const float*)d_in[0];   // [16384, 512] fp32
    const float* W = (const float*)d_in[1];   // [512, 512] fp32
    float* out = (float*)d_out;               // [16384, 512] fp32
    unsigned short* Wf = (unsigned short*)d_ws;   // 512 KB bf16 fragments (K-prescaled)

    wprep_kernel<<<128, 256, 0, stream>>>(W, Wf);
    fixpoint_kernel<<<BATCH / TM, 512, 0, stream>>>(x, Wf, out);
}

// Round 7
// 499.698 us; speedup vs baseline: 1.3632x; 1.0419x over previous
//
#include <hip/hip_runtime.h>

// z <- tanh(z @ W^T + x), 50 fixed-point steps. B=16384, D=512.
// Persistent-block: each of 256 blocks owns 64 rows of z, DOUBLE-buffered in
// LDS as bf16 (2 x 64 KB) -> ONE barrier per iteration (epi writes the other
// buffer; round-4's regression of this structure was proven in round 5/6 to
// be the x L2-thrash, which is now gone: FETCH 496 MB -> 18.5 MB).
// x lives in 32 packed-fp16 VGPRs per thread (64 halves, fragment order,
// loaded once; NOT 64 f32 like round 1's spill). Round-6 showed per-iter
// global x reads thrash L2; LDS can't hold x + double-z (192 KB > 160 KB),
// registers are the only spot. All x indices compile-time (no scratch).
// W pre-scaled by K = 2*log2(e) as bf16 MFMA A-fragments in d_ws (512 KB,
// L2-resident, streamed; register-resident W impossible: 128 arch-VGPR cap).
// Epilogue: s = fmaf((float)x_f16, K, acc) [v_fma_mix]; tanh = 1 -
// 2/(exp2(med3(s,+-CL))+1); pack via v_cvt_pk_bf16_f32.
// Register budget: acc 64 + x 32 + staging/addr ~24 = ~120 < 128.

typedef short s8v  __attribute__((ext_vector_type(8)));   // 8 bf16 = 4 VGPRs
typedef float f32x16 __attribute__((ext_vector_type(16)));
typedef _Float16 h4 __attribute__((ext_vector_type(4)));  // 4 fp16 = 2 VGPRs

#define BATCH 16384
#define DIM   512
#define TM    64        // rows per block
#define NITER 50        // 1 init step + 49 GEMM steps

#define KSC 2.8853900817779268f    // 2*log2(e)
#define KCL 28.853900817779268f    // 10*KSC: tanh(+-10) == +-1 in fp32

__device__ __forceinline__ unsigned short f2bf(float f) {
    unsigned int u = __float_as_uint(f);
    u += 0x7fffu + ((u >> 16) & 1u);          // round-to-nearest-even
    return (unsigned short)(u >> 16);
}

// W (fp32 [512][512] row-major) -> K-prescaled bf16 A-fragments for
// v_mfma_f32_32x32x16_bf16. Granule tid = (jt*32 + ks)*64 + lane holds
// K*W[j = 32*jt + (lane&31)][k = 16*ks + 8*(lane>>5) .. +8] as 16 B.
__global__ void wprep_kernel(const float* __restrict__ W, unsigned short* __restrict__ Wf) {
    int tid = blockIdx.x * blockDim.x + threadIdx.x;   // 0..32767
    int jt  = tid >> 11;
    int rem = tid & 2047;
    int ks  = rem >> 6;
    int L   = rem & 63;
    int j   = jt * 32 + (L & 31);
    int k   = ks * 16 + (L >> 5) * 8;
    const float* src = W + j * DIM + k;
    uint4 p;
    p.x = (unsigned)f2bf(src[0] * KSC) | ((unsigned)f2bf(src[1] * KSC) << 16);
    p.y = (unsigned)f2bf(src[2] * KSC) | ((unsigned)f2bf(src[3] * KSC) << 16);
    p.z = (unsigned)f2bf(src[4] * KSC) | ((unsigned)f2bf(src[5] * KSC) << 16);
    p.w = (unsigned)f2bf(src[6] * KSC) | ((unsigned)f2bf(src[7] * KSC) << 16);
    ((uint4*)Wf)[tid] = p;
}

// LDS z layout: row r x 512 bf16, 64 chunks of 16 B per row, XOR swizzle
// chunk' = chunk ^ (r & 7) -> spreads bank groups for ds_read_b128 / writes.
__device__ __forceinline__ int z_addr(int r, int j) {   // element index
    int c  = j >> 3;
    int lo = j & 7;
    return r * DIM + (((c ^ (r & 7)) << 3) | lo);
}

__device__ __forceinline__ unsigned pk_bf16(float lo, float hi) {
    unsigned r;
    asm("v_cvt_pk_bf16_f32 %0, %1, %2" : "=v"(r) : "v"(lo), "v"(hi));  // RNE
    return r;
}

// s is the ALREADY K-SCALED argument: tanh(v) where s = K*v.
__device__ __forceinline__ float tanh_pre(float s) {
    s = __builtin_amdgcn_fmed3f(s, -KCL, KCL);
    float t = __builtin_amdgcn_exp2f(s);
    float q = __builtin_amdgcn_rcpf(t + 1.0f);
    return fmaf(-2.0f, q, 1.0f);            // (t-1)/(t+1) == 1 - 2/(t+1)
}

__device__ __forceinline__ f32x16 zero16() {
    f32x16 v;
#pragma unroll
    for (int i = 0; i < 16; ++i) v[i] = 0.0f;
    return v;
}

__device__ __forceinline__ h4 cvt_h4(float4 t) {
    h4 r;
    r[0] = (_Float16)t.x; r[1] = (_Float16)t.y;
    r[2] = (_Float16)t.z; r[3] = (_Float16)t.w;
    return r;
}

__global__ __launch_bounds__(512, 2)
void fixpoint_kernel(const float* __restrict__ x,
                     const unsigned short* __restrict__ Wf,
                     float* __restrict__ out) {
    __shared__ alignas(16) unsigned short zt[2][TM * DIM];   // 128 KB double buffer

    const int tid  = threadIdx.x;
    const int lane = tid & 63;
    const int w    = tid >> 6;       // wave 0..7, owns j-slab [64w, 64w+64)
    const int l31  = lane & 31;
    const int h    = lane >> 5;      // k-half for A/B fragments
    const int r0   = blockIdx.x * TM;
    const int jt0  = 2 * w;
    const int jb0  = 64 * w;
    const int swz  = l31 & 7;        // z-row swizzle key

    const s8v* Wfv = (const s8v*)Wf;

    // ---- x -> 32 packed-fp16 VGPRs, fragment order (the ONLY global x read) ----
    // frag0: row l31, cols j0(g)..+3 ; frag1: row l31+32 ; frag2/3: same, +32 cols
    h4 xf0[4], xf1[4], xf2[4], xf3[4];
    {
        const float* xr0 = x + (size_t)(r0 + l31) * DIM;
        const float* xr1 = x + (size_t)(r0 + l31 + 32) * DIM;
#pragma unroll
        for (int g = 0; g < 4; ++g) {
            const int j0 = jb0 + 8 * g + 4 * h;
            xf0[g] = cvt_h4(*(const float4*)&xr0[j0]);
            xf1[g] = cvt_h4(*(const float4*)&xr1[j0]);
            xf2[g] = cvt_h4(*(const float4*)&xr0[j0 + 32]);
            xf3[g] = cvt_h4(*(const float4*)&xr1[j0 + 32]);
        }
    }

    f32x16 ac0, ac1, ac2, ac3;

    // epilogue -> bf16 z into zn. acc layout: col = lane&31 -> z-row;
    // row = (reg&3)+8*(reg>>2)+4*h -> j.
    auto epi_z = [&](unsigned short* __restrict__ zn) {
#pragma unroll
        for (int g = 0; g < 4; ++g) {
            const int j0 = jb0 + 8 * g + 4 * h;
            uint2 p;
            p.x = pk_bf16(tanh_pre(fmaf((float)xf0[g][0], KSC, ac0[4*g+0])),
                          tanh_pre(fmaf((float)xf0[g][1], KSC, ac0[4*g+1])));
            p.y = pk_bf16(tanh_pre(fmaf((float)xf0[g][2], KSC, ac0[4*g+2])),
                          tanh_pre(fmaf((float)xf0[g][3], KSC, ac0[4*g+3])));
            *(uint2*)&zn[z_addr(l31, j0)] = p;
            p.x = pk_bf16(tanh_pre(fmaf((float)xf1[g][0], KSC, ac1[4*g+0])),
                          tanh_pre(fmaf((float)xf1[g][1], KSC, ac1[4*g+1])));
            p.y = pk_bf16(tanh_pre(fmaf((float)xf1[g][2], KSC, ac1[4*g+2])),
                          tanh_pre(fmaf((float)xf1[g][3], KSC, ac1[4*g+3])));
            *(uint2*)&zn[z_addr(l31 + 32, j0)] = p;
            p.x = pk_bf16(tanh_pre(fmaf((float)xf2[g][0], KSC, ac2[4*g+0])),
                          tanh_pre(fmaf((float)xf2[g][1], KSC, ac2[4*g+1])));
            p.y = pk_bf16(tanh_pre(fmaf((float)xf2[g][2], KSC, ac2[4*g+2])),
                          tanh_pre(fmaf((float)xf2[g][3], KSC, ac2[4*g+3])));
            *(uint2*)&zn[z_addr(l31, j0 + 32)] = p;
            p.x = pk_bf16(tanh_pre(fmaf((float)xf3[g][0], KSC, ac3[4*g+0])),
                          tanh_pre(fmaf((float)xf3[g][1], KSC, ac3[4*g+1])));
            p.y = pk_bf16(tanh_pre(fmaf((float)xf3[g][2], KSC, ac3[4*g+2])),
                          tanh_pre(fmaf((float)xf3[g][3], KSC, ac3[4*g+3])));
            *(uint2*)&zn[z_addr(l31 + 32, j0 + 32)] = p;
        }
    };

    auto epi_out = [&]() {
        float* o0 = out + (size_t)(r0 + l31) * DIM;
        float* o1 = out + (size_t)(r0 + l31 + 32) * DIM;
#pragma unroll
        for (int g = 0; g < 4; ++g) {
            const int j0 = jb0 + 8 * g + 4 * h;
            float4 v;
            v.x = tanh_pre(fmaf((float)xf0[g][0], KSC, ac0[4*g+0]));
            v.y = tanh_pre(fmaf((float)xf0[g][1], KSC, ac0[4*g+1]));
            v.z = tanh_pre(fmaf((float)xf0[g][2], KSC, ac0[4*g+2]));
            v.w = tanh_pre(fmaf((float)xf0[g][3], KSC, ac0[4*g+3]));
            *(float4*)&o0[j0] = v;
            v.x = tanh_pre(fmaf((float)xf1[g][0], KSC, ac1[4*g+0]));
            v.y = tanh_pre(fmaf((float)xf1[g][1], KSC, ac1[4*g+1]));
            v.z = tanh_pre(fmaf((float)xf1[g][2], KSC, ac1[4*g+2]));
            v.w = tanh_pre(fmaf((float)xf1[g][3], KSC, ac1[4*g+3]));
            *(float4*)&o1[j0] = v;
            v.x = tanh_pre(fmaf((float)xf2[g][0], KSC, ac2[4*g+0]));
            v.y = tanh_pre(fmaf((float)xf2[g][1], KSC, ac2[4*g+1]));
            v.z = tanh_pre(fmaf((float)xf2[g][2], KSC, ac2[4*g+2]));
            v.w = tanh_pre(fmaf((float)xf2[g][3], KSC, ac2[4*g+3]));
            *(float4*)&o0[j0 + 32] = v;
            v.x = tanh_pre(fmaf((float)xf3[g][0], KSC, ac3[4*g+0]));
            v.y = tanh_pre(fmaf((float)xf3[g][1], KSC, ac3[4*g+1]));
            v.z = tanh_pre(fmaf((float)xf3[g][2], KSC, ac3[4*g+2]));
            v.w = tanh_pre(fmaf((float)xf3[g][3], KSC, ac3[4*g+3]));
            *(float4*)&o1[j0 + 32] = v;
        }
    };

    auto gemm = [&](const unsigned short* __restrict__ zc) {
        ac0 = zero16(); ac1 = zero16(); ac2 = zero16(); ac3 = zero16();
#pragma unroll 4
        for (int ks = 0; ks < 32; ++ks) {
            s8v a0 = Wfv[(jt0 * 32 + ks) * 64 + lane];
            s8v a1 = Wfv[((jt0 + 1) * 32 + ks) * 64 + lane];
            const int c = ((2 * ks + h) ^ swz) << 3;
            s8v b0 = *(const s8v*)&zc[l31 * DIM + c];
            s8v b1 = *(const s8v*)&zc[(l31 + 32) * DIM + c];
            ac0 = __builtin_amdgcn_mfma_f32_32x32x16_bf16(a0, b0, ac0, 0, 0, 0);
            ac1 = __builtin_amdgcn_mfma_f32_32x32x16_bf16(a0, b1, ac1, 0, 0, 0);
            ac2 = __builtin_amdgcn_mfma_f32_32x32x16_bf16(a1, b0, ac2, 0, 0, 0);
            ac3 = __builtin_amdgcn_mfma_f32_32x32x16_bf16(a1, b1, ac3, 0, 0, 0);
        }
    };

    // ---- step 1: z0 = tanh(K*x) via the epilogue path with zero acc ----
    ac0 = zero16(); ac1 = zero16(); ac2 = zero16(); ac3 = zero16();
    epi_z(zt[0]);
    __syncthreads();

    int cur = 0;
#pragma unroll 1
    for (int it = 0; it < NITER - 2; ++it) {     // 48 LDS->LDS steps
        gemm(zt[cur]);
        epi_z(zt[cur ^ 1]);   // other buffer: safe vs lagging waves' gemm reads
        __syncthreads();      // single barrier: writes visible, flip together
        cur ^= 1;
    }
    // ---- step 50: fp32 store to out ----
    gemm(zt[cur]);
    epi_out();
}

extern "C" void kernel_launch(void* const* d_in, const int* in_sizes, int n_in,
                              void* d_out, int out_size, void* d_ws, size_t ws_size,
                              hipStream_t stream) {
    const float* x = (const float*)d_in[0];   // [16384, 512] fp32
    const float* W = (const float*)d_in[1];   // [512, 512] fp32
    float* out = (float*)d_out;               // [16384, 512] fp32
    unsigned short* Wf = (unsigned short*)d_ws;   // 512 KB bf16 fragments (K-prescaled)

    wprep_kernel<<<128, 256, 0, stream>>>(W, Wf);
    fixpoint_kernel<<<BATCH / TM, 512, 0, stream>>>(x, Wf, out);
}